// Round 22
// baseline (117.668 us; speedup 1.0000x reference)
//
#include <hip/hip_runtime.h>
#include <stdint.h>

typedef __attribute__((ext_vector_type(8))) short short8;
typedef __attribute__((ext_vector_type(8))) __bf16 bf16x8;
typedef __attribute__((ext_vector_type(4))) float f32x4;
typedef __attribute__((ext_vector_type(2))) unsigned int u32x2;

#define T_SEQ 2048

// round-to-nearest-even f32 -> bf16
static __device__ __forceinline__ ushort f2bf(float f) {
  uint32_t u = __float_as_uint(f);
  u += 0x7fffu + ((u >> 16) & 1u);
  return (ushort)(u >> 16);
}

// packed f32x2 -> bf16x2 (low = lo, high = hi), HW RNE
static __device__ __forceinline__ uint32_t cvtpk(float lo, float hi) {
  uint32_t r;
  asm("v_cvt_pk_bf16_f32 %0, %1, %2" : "=v"(r) : "v"(lo), "v"(hi));
  return r;
}

static __device__ __forceinline__ f32x4 mfma16(short8 a, short8 b, f32x4 c) {
  return __builtin_amdgcn_mfma_f32_16x16x32_bf16(
      __builtin_bit_cast(bf16x8, a), __builtin_bit_cast(bf16x8, b), c, 0, 0, 0);
}

// async global->LDS, 16B per lane; lds base must be wave-uniform
static __device__ __forceinline__ void gload16(const ushort* g, char* l) {
  __builtin_amdgcn_global_load_lds(
      (const __attribute__((address_space(1))) void*)g,
      (__attribute__((address_space(3))) void*)l, 16, 0, 0);
}

// Fused prologue: blocks <2048 convert x f32->bf16 (8 elems/thread);
// blocks >=2048 transpose+convert Wqkv (tb<768) / Wo into [N][K] bf16.
__global__ __launch_bounds__(256) void prep_k(const float* __restrict__ x,
                                              const float* __restrict__ Wqkv,
                                              const float* __restrict__ Wo,
                                              ushort* __restrict__ xb,
                                              ushort* __restrict__ WqkvT,
                                              ushort* __restrict__ WoT) {
  if (blockIdx.x < 2048) {
    int i = (blockIdx.x * 256 + threadIdx.x) * 8;
    float4 a = *(const float4*)(x + i);
    float4 b = *(const float4*)(x + i + 4);
    short8 o;
    ((ushort*)&o)[0] = f2bf(a.x); ((ushort*)&o)[1] = f2bf(a.y);
    ((ushort*)&o)[2] = f2bf(a.z); ((ushort*)&o)[3] = f2bf(a.w);
    ((ushort*)&o)[4] = f2bf(b.x); ((ushort*)&o)[5] = f2bf(b.y);
    ((ushort*)&o)[6] = f2bf(b.z); ((ushort*)&o)[7] = f2bf(b.w);
    *(short8*)(xb + i) = o;
    return;
  }
  __shared__ ushort t[64][65];
  int tb = blockIdx.x - 2048;       // 0..1023
  const float* in;
  ushort* out;
  int N, byl;
  if (tb < 768) { in = Wqkv; out = WqkvT; N = 3072; byl = tb >> 4; }
  else          { in = Wo;   out = WoT;   N = 1024; byl = (tb - 768) >> 4; }
  const int K = 1024;
  const int bk = (tb & 15) * 64, bn = byl * 64;
  const int r = threadIdx.x >> 2, c0 = (threadIdx.x & 3) << 4;
  const float* src = in + (size_t)(bk + r) * N + bn + c0;
#pragma unroll
  for (int q = 0; q < 4; ++q) {
    float4 a = *(const float4*)(src + q * 4);
    t[r][c0 + q * 4 + 0] = f2bf(a.x);
    t[r][c0 + q * 4 + 1] = f2bf(a.y);
    t[r][c0 + q * 4 + 2] = f2bf(a.z);
    t[r][c0 + q * 4 + 3] = f2bf(a.w);
  }
  __syncthreads();
  short8 o0, o1;
#pragma unroll
  for (int j = 0; j < 8; ++j) {
    ((ushort*)&o0)[j] = t[c0 + j][r];
    ((ushort*)&o1)[j] = t[c0 + 8 + j][r];
  }
  ushort* dst = out + (size_t)(bn + r) * K + bk + c0;
  *(short8*)(dst) = o0;
  *(short8*)(dst + 8) = o1;
}

// 256x192-tile GEMM (full-machine grid 16x16 = 256 blocks = 1/CU), BK=64,
// 384 thr = 6 waves (2m x 3n), per-wave output 128x64 (identical to the
// proven gemm256 wave geometry). Double-buffered LDS + counted vmcnt (T3/T4).
// Chunks: A 2048 + B 1536 = 3584 = 9.33/thread; entry vmcnt(9) still drains
// tile t (t's loads are oldest). No wave straddles the A/B boundary (2048 =
// wave-base 128 + 5*384), so the wave-uniform LDS base stays legal.
__global__ __launch_bounds__(384) void gemm192(const ushort* __restrict__ A,
                                               const ushort* __restrict__ Bt,
                                               ushort* __restrict__ C,
                                               int Ndim) {
  __shared__ char sA[2][32768];   // 256 rows x 128B, swizzled
  __shared__ char sB[2][24576];   // 192 rows x 128B, swizzled
  const int tid = threadIdx.x;
  const int lane = tid & 63, wid = tid >> 6;    // 6 waves
  const int wm = (wid >= 3) ? 1 : 0, wn = wid - wm * 3;
  const int lc = lane & 15, lg = lane >> 4;
  const int bm = blockIdx.x * 256, bn = blockIdx.y * 192;
  const int lane16 = lane << 4;

  f32x4 acc[8][4] = {};

#define STAGE192(tt, bb)                                                    \
  do {                                                                      \
    _Pragma("unroll") for (int i_ = 0; i_ < 10; ++i_) {                     \
      int c_ = tid + i_ * 384;                                              \
      if (c_ < 3584) {                                                      \
        if (c_ < 2048) {                                                    \
          int row_ = c_ >> 3;                                               \
          int cbl_ = (c_ & 7) << 4;                                         \
          int ce_ = (cbl_ ^ ((row_ & 7) << 4)) >> 1;                        \
          gload16(A + (size_t)(bm + row_) * 1024 + (tt) * 64 + ce_,         \
                  sA[bb] + ((c_ << 4) - lane16));                           \
        } else {                                                            \
          int c2_ = c_ - 2048;                                              \
          int row_ = c2_ >> 3;                                              \
          int cbl_ = (c2_ & 7) << 4;                                        \
          int ce_ = (cbl_ ^ ((row_ & 7) << 4)) >> 1;                        \
          gload16(Bt + (size_t)(bn + row_) * 1024 + (tt) * 64 + ce_,        \
                  sB[bb] + ((c2_ << 4) - lane16));                          \
        }                                                                   \
      }                                                                     \
    }                                                                       \
  } while (0)

  STAGE192(0, 0);
  STAGE192(1, 1);

  for (int t = 0; t < 16; ++t) {
    const int cur = t & 1;
    if (t < 15) asm volatile("s_waitcnt vmcnt(9)" ::: "memory");
    else        asm volatile("s_waitcnt vmcnt(0)" ::: "memory");
    __builtin_amdgcn_s_barrier();
    __builtin_amdgcn_sched_barrier(0);
#pragma unroll
    for (int ks = 0; ks < 2; ++ks) {
      const int kb = ks * 64 + lg * 16;
      short8 bf[4];
#pragma unroll
      for (int nf = 0; nf < 4; ++nf) {
        int row = wn * 64 + nf * 16 + lc;
        bf[nf] = *(const short8*)&sB[cur][(row << 7) + (kb ^ ((row & 7) << 4))];
      }
#pragma unroll
      for (int mh = 0; mh < 2; ++mh) {
        short8 af[4];
#pragma unroll
        for (int mf = 0; mf < 4; ++mf) {
          int row = wm * 128 + mh * 64 + mf * 16 + lc;
          af[mf] = *(const short8*)&sA[cur][(row << 7) + (kb ^ ((row & 7) << 4))];
        }
        __builtin_amdgcn_s_setprio(1);
#pragma unroll
        for (int mf = 0; mf < 4; ++mf)
#pragma unroll
          for (int nf = 0; nf < 4; ++nf)
            acc[mh * 4 + mf][nf] = mfma16(af[mf], bf[nf], acc[mh * 4 + mf][nf]);
        __builtin_amdgcn_s_setprio(0);
      }
    }
    asm volatile("s_waitcnt lgkmcnt(0)" ::: "memory");
    __builtin_amdgcn_sched_barrier(0);
    __builtin_amdgcn_s_barrier();
    __builtin_amdgcn_sched_barrier(0);
    if (t + 2 < 16) STAGE192(t + 2, cur);
  }
#undef STAGE192

#pragma unroll
  for (int mf = 0; mf < 8; ++mf) {
    int rowb = bm + wm * 128 + mf * 16 + lg * 4;
#pragma unroll
    for (int nf = 0; nf < 4; ++nf) {
      int col = bn + wn * 64 + nf * 16 + lc;
#pragma unroll
      for (int r = 0; r < 4; ++r)
        C[(size_t)(rowb + r) * Ndim + col] = f2bf(acc[mf][nf][r]);
    }
  }
}

// 128x128-tile GEMM, double-buffered LDS + counted vmcnt (proven round 21).
__global__ __launch_bounds__(256) void gemm128p(const ushort* __restrict__ A,
                                                const ushort* __restrict__ Bt,
                                                void* __restrict__ Cv,
                                                int Ndim, int Kdim, int f32out) {
  __shared__ char sA[2][16384];
  __shared__ char sB[2][16384];
  const int tid = threadIdx.x;
  const int lane = tid & 63, wid = tid >> 6;
  const int wm = wid >> 1, wn = wid & 1;
  const int lc = lane & 15, lg = lane >> 4;
  const int bm = blockIdx.x * 128, bn = blockIdx.y * 128;
  const int lane16 = lane << 4;
  const int nk = Kdim >> 6;

  f32x4 acc[4][4] = {};

#define STAGE128(tt, bb)                                                   \
  do {                                                                     \
    _Pragma("unroll") for (int i_ = 0; i_ < 4; ++i_) {                     \
      int v_ = tid + i_ * 256;                                             \
      int row_ = v_ >> 3;                                                  \
      int cbl_ = (v_ & 7) << 4;                                            \
      int ce_ = (cbl_ ^ ((row_ & 7) << 4)) >> 1;                           \
      char* la_ = sA[bb] + ((v_ << 4) - lane16);                           \
      char* lb_ = sB[bb] + ((v_ << 4) - lane16);                           \
      gload16(A + (size_t)(bm + row_) * Kdim + (tt) * 64 + ce_, la_);      \
      gload16(Bt + (size_t)(bn + row_) * Kdim + (tt) * 64 + ce_, lb_);     \
    }                                                                      \
  } while (0)

  STAGE128(0, 0);
  STAGE128(1, 1);

  for (int t = 0; t < nk; ++t) {
    const int cur = t & 1;
    if (t < nk - 1) asm volatile("s_waitcnt vmcnt(8)" ::: "memory");
    else            asm volatile("s_waitcnt vmcnt(0)" ::: "memory");
    __builtin_amdgcn_s_barrier();
    __builtin_amdgcn_sched_barrier(0);
#pragma unroll
    for (int ks = 0; ks < 2; ++ks) {
      const int kb = ks * 64 + lg * 16;
      short8 af[4], bfr[4];
#pragma unroll
      for (int m = 0; m < 4; ++m) {
        int row = wm * 64 + m * 16 + lc;
        af[m] = *(const short8*)&sA[cur][(row << 7) + (kb ^ ((row & 7) << 4))];
      }
#pragma unroll
      for (int n = 0; n < 4; ++n) {
        int row = wn * 64 + n * 16 + lc;
        bfr[n] = *(const short8*)&sB[cur][(row << 7) + (kb ^ ((row & 7) << 4))];
      }
      __builtin_amdgcn_s_setprio(1);
#pragma unroll
      for (int m = 0; m < 4; ++m)
#pragma unroll
        for (int n = 0; n < 4; ++n)
          acc[m][n] = mfma16(af[m], bfr[n], acc[m][n]);
      __builtin_amdgcn_s_setprio(0);
    }
    asm volatile("s_waitcnt lgkmcnt(0)" ::: "memory");
    __builtin_amdgcn_sched_barrier(0);
    __builtin_amdgcn_s_barrier();
    __builtin_amdgcn_sched_barrier(0);
    if (t + 2 < nk) STAGE128(t + 2, cur);
  }
#undef STAGE128

#pragma unroll
  for (int m = 0; m < 4; ++m) {
    int rowb = bm + wm * 64 + m * 16 + lg * 4;
#pragma unroll
    for (int n = 0; n < 4; ++n) {
      int col = bn + wn * 64 + n * 16 + lc;
      if (f32out) {
        float* C = (float*)Cv;
#pragma unroll
        for (int r = 0; r < 4; ++r)
          C[(size_t)(rowb + r) * Ndim + col] = acc[m][n][r];
      } else {
        ushort* C = (ushort*)Cv;
#pragma unroll
        for (int r = 0; r < 4; ++r)
          C[(size_t)(rowb + r) * Ndim + col] = f2bf(acc[m][n][r]);
      }
    }
  }
}

// Flash attention (round-17 proven: 52.9 us): 512 thr / 8 waves x 16 q rows,
// bijective slot map (causal pairing t/15-t per CU + XCD locality), 2
// barriers/iter, reg-prefetched K/V, swapped QK^T, fixed-max softmax,
// deferred denominator, cvt_pk P-pack via per-wave LDS.
__global__ __launch_bounds__(512) void attn_k(const ushort* __restrict__ qkv,
                                              ushort* __restrict__ Y) {
  __shared__ char sK[8192];
  __shared__ char sV[8192];
  __shared__ char sP[16384];
  __shared__ float sL[8][16];
  const int tid = threadIdx.x;
  const int lane = tid & 63, wid = tid >> 6;
  const int lc = lane & 15, lg = lane >> 4;
  const int orig = blockIdx.x;
  const int xcd = orig & 7, slot = orig >> 3;
  int tile, bhl;
  if (slot < 32) { tile = slot >> 2;              bhl = slot & 3; }
  else           { tile = 15 - ((slot - 32) >> 2); bhl = (slot - 32) & 3; }
  const int bh = xcd * 4 + bhl;
  const int b = bh >> 4, h = bh & 15;
  char* sPw = sP + (wid << 11);

  const ushort* base = qkv + (size_t)b * T_SEQ * 3072 + h * 64;
  const int q0 = tile * 128 + wid * 16;

  const int kt = tid >> 3, kce = (tid & 7) << 3, kcb = kce << 1;
  const int ksw = (kt & 7) << 4;
  const int vt = tid & 63, vd0 = (tid >> 6) << 3;
  const ushort* kbase = base + 1024;
  const ushort* vbase = base + 2048;

  short8 qf[2];
#pragma unroll
  for (int ks = 0; ks < 2; ++ks)
    qf[ks] = *(const short8*)(base + (size_t)(q0 + lc) * 3072 + ks * 32 + lg * 8);

  f32x4 o[4] = {};
  float lsum = 0.f;

  const float cexp = 0.125f * 1.4426950408889634f;
  const int nkb = 2 * (tile + 1);
  const int qmaxw = q0 + 15;

  short8 kr = *(const short8*)(kbase + (size_t)kt * 3072 + kce);
  short8 vr = *(const short8*)(vbase + (size_t)vt * 3072 + vd0);

  for (int kb = 0; kb < nkb; ++kb) {
    __syncthreads();
    *(short8*)&sK[(kt << 7) + (kcb ^ ksw)] = kr;
#pragma unroll
    for (int j = 0; j < 8; ++j) {
      int d = vd0 + j;
      *(ushort*)&sV[(d << 7) + ((2 * vt) ^ ((d & 7) << 4))] = ((const ushort*)&vr)[j];
    }
    __syncthreads();
    if (kb + 1 < nkb) {
      kr = *(const short8*)(kbase + (size_t)((kb + 1) * 64 + kt) * 3072 + kce);
      vr = *(const short8*)(vbase + (size_t)((kb + 1) * 64 + vt) * 3072 + vd0);
    }
    if (kb * 64 > qmaxw) continue;

    f32x4 S[4] = {};
    __builtin_amdgcn_s_setprio(1);
#pragma unroll
    for (int ks = 0; ks < 2; ++ks) {
      int kbyt = ks * 64 + lg * 16;
      short8 kf[4];
#pragma unroll
      for (int n = 0; n < 4; ++n) {
        int row = n * 16 + lc;
        kf[n] = *(const short8*)&sK[(row << 7) + (kbyt ^ ((row & 7) << 4))];
      }
#pragma unroll
      for (int n = 0; n < 4; ++n)
        S[n] = mfma16(kf[n], qf[ks], S[n]);
    }
    __builtin_amdgcn_s_setprio(0);

    const bool diag = (kb * 64 + 63 > q0);
    {
      int q = q0 + lc;
      float lacc = 0.f;
#pragma unroll
      for (int n = 0; n < 4; ++n) {
        int kg = kb * 64 + n * 16 + lg * 4;
        f32x4 pe;
#pragma unroll
        for (int r = 0; r < 4; ++r) {
          pe[r] = exp2f(S[n][r] * cexp);
          if (diag && (kg + r > q)) pe[r] = 0.f;
        }
        lacc += (pe[0] + pe[1]) + (pe[2] + pe[3]);
        u32x2 w;
        w[0] = cvtpk(pe[0], pe[1]);
        w[1] = cvtpk(pe[2], pe[3]);
        int colb = n * 32 + lg * 8;
        *(u32x2*)&sPw[(lc << 7) + (colb ^ ((lc & 7) << 4))] = w;
      }
      lsum += lacc;
    }
    asm volatile("" ::: "memory");
    __builtin_amdgcn_s_setprio(1);
#pragma unroll
    for (int ks = 0; ks < 2; ++ks) {
      int kbyt = ks * 64 + lg * 16;
      short8 pf = *(const short8*)&sPw[(lc << 7) + (kbyt ^ ((lc & 7) << 4))];
      short8 vf[4];
#pragma unroll
      for (int dn = 0; dn < 4; ++dn) {
        int row = dn * 16 + lc;
        vf[dn] = *(const short8*)&sV[(row << 7) + (kbyt ^ ((row & 7) << 4))];
      }
#pragma unroll
      for (int dn = 0; dn < 4; ++dn)
        o[dn] = mfma16(pf, vf[dn], o[dn]);
    }
    __builtin_amdgcn_s_setprio(0);
  }
  {
    float v = lsum;
    v += __shfl_xor(v, 16);
    v += __shfl_xor(v, 32);
    sL[wid][lc] = 1.0f / v;
  }
  asm volatile("" ::: "memory");
  {
    float lr[4];
#pragma unroll
    for (int r = 0; r < 4; ++r) lr[r] = sL[wid][lg * 4 + r];
#pragma unroll
    for (int dn = 0; dn < 4; ++dn) {
#pragma unroll
      for (int r = 0; r < 4; ++r) {
        int t = q0 + lg * 4 + r;
        Y[(size_t)(b * T_SEQ + t) * 1024 + h * 64 + dn * 16 + lc] =
            f2bf(o[dn][r] * lr[r]);
      }
    }
  }
}

extern "C" void kernel_launch(void* const* d_in, const int* in_sizes, int n_in,
                              void* d_out, int out_size, void* d_ws, size_t ws_size,
                              hipStream_t stream) {
  const float* x    = (const float*)d_in[0];
  const float* Wqkv = (const float*)d_in[1];
  const float* Wo   = (const float*)d_in[2];
  for (int i = 0; i < n_in; ++i) {
    if (in_sizes[i] == 4194304) x = (const float*)d_in[i];
    else if (in_sizes[i] == 3145728) Wqkv = (const float*)d_in[i];
    else if (in_sizes[i] == 1048576) Wo = (const float*)d_in[i];
  }
  float* out = (float*)d_out;

  ushort* xb    = (ushort*)d_ws;                       // [4096][1024] bf16
  ushort* WqkvT = xb + (size_t)4096 * 1024;            // [3072][1024]
  ushort* WoT   = WqkvT + (size_t)3072 * 1024;         // [1024][1024]
  ushort* QKV   = WoT + (size_t)1024 * 1024;           // [4096][3072]
  ushort* Yb    = QKV + (size_t)4096 * 3072;           // [4096][1024]

  prep_k<<<3072, 256, 0, stream>>>(x, Wqkv, Wo, xb, WqkvT, WoT);
  gemm192<<<dim3(16, 16), 384, 0, stream>>>(xb, WqkvT, QKV, 3072);
  attn_k<<<512, 512, 0, stream>>>(QKV, Yb);
  gemm128p<<<dim3(32, 8), 256, 0, stream>>>(Yb, WoT, out, 1024, 1024, 1);
}

// Round 23
// 108.771 us; speedup vs baseline: 1.0818x; 1.0818x over previous
//
#include <hip/hip_runtime.h>
#include <stdint.h>

typedef __attribute__((ext_vector_type(8))) short short8;
typedef __attribute__((ext_vector_type(8))) __bf16 bf16x8;
typedef __attribute__((ext_vector_type(4))) float f32x4;
typedef __attribute__((ext_vector_type(2))) unsigned int u32x2;

#define T_SEQ 2048

// round-to-nearest-even f32 -> bf16
static __device__ __forceinline__ ushort f2bf(float f) {
  uint32_t u = __float_as_uint(f);
  u += 0x7fffu + ((u >> 16) & 1u);
  return (ushort)(u >> 16);
}

// packed f32x2 -> bf16x2 (low = lo, high = hi), HW RNE
static __device__ __forceinline__ uint32_t cvtpk(float lo, float hi) {
  uint32_t r;
  asm("v_cvt_pk_bf16_f32 %0, %1, %2" : "=v"(r) : "v"(lo), "v"(hi));
  return r;
}

static __device__ __forceinline__ f32x4 mfma16(short8 a, short8 b, f32x4 c) {
  return __builtin_amdgcn_mfma_f32_16x16x32_bf16(
      __builtin_bit_cast(bf16x8, a), __builtin_bit_cast(bf16x8, b), c, 0, 0, 0);
}

// async global->LDS, 16B per lane; lds base must be wave-uniform
static __device__ __forceinline__ void gload16(const ushort* g, char* l) {
  __builtin_amdgcn_global_load_lds(
      (const __attribute__((address_space(1))) void*)g,
      (__attribute__((address_space(3))) void*)l, 16, 0, 0);
}

// Fused prologue: blocks <2048 convert x f32->bf16 (8 elems/thread);
// blocks >=2048 transpose+convert Wqkv (tb<768) / Wo into [N][K] bf16.
__global__ __launch_bounds__(256) void prep_k(const float* __restrict__ x,
                                              const float* __restrict__ Wqkv,
                                              const float* __restrict__ Wo,
                                              ushort* __restrict__ xb,
                                              ushort* __restrict__ WqkvT,
                                              ushort* __restrict__ WoT) {
  if (blockIdx.x < 2048) {
    int i = (blockIdx.x * 256 + threadIdx.x) * 8;
    float4 a = *(const float4*)(x + i);
    float4 b = *(const float4*)(x + i + 4);
    short8 o;
    ((ushort*)&o)[0] = f2bf(a.x); ((ushort*)&o)[1] = f2bf(a.y);
    ((ushort*)&o)[2] = f2bf(a.z); ((ushort*)&o)[3] = f2bf(a.w);
    ((ushort*)&o)[4] = f2bf(b.x); ((ushort*)&o)[5] = f2bf(b.y);
    ((ushort*)&o)[6] = f2bf(b.z); ((ushort*)&o)[7] = f2bf(b.w);
    *(short8*)(xb + i) = o;
    return;
  }
  __shared__ ushort t[64][65];
  int tb = blockIdx.x - 2048;       // 0..1023
  const float* in;
  ushort* out;
  int N, byl;
  if (tb < 768) { in = Wqkv; out = WqkvT; N = 3072; byl = tb >> 4; }
  else          { in = Wo;   out = WoT;   N = 1024; byl = (tb - 768) >> 4; }
  const int K = 1024;
  const int bk = (tb & 15) * 64, bn = byl * 64;
  const int r = threadIdx.x >> 2, c0 = (threadIdx.x & 3) << 4;
  const float* src = in + (size_t)(bk + r) * N + bn + c0;
#pragma unroll
  for (int q = 0; q < 4; ++q) {
    float4 a = *(const float4*)(src + q * 4);
    t[r][c0 + q * 4 + 0] = f2bf(a.x);
    t[r][c0 + q * 4 + 1] = f2bf(a.y);
    t[r][c0 + q * 4 + 2] = f2bf(a.z);
    t[r][c0 + q * 4 + 3] = f2bf(a.w);
  }
  __syncthreads();
  short8 o0, o1;
#pragma unroll
  for (int j = 0; j < 8; ++j) {
    ((ushort*)&o0)[j] = t[c0 + j][r];
    ((ushort*)&o1)[j] = t[c0 + 8 + j][r];
  }
  ushort* dst = out + (size_t)(bn + r) * K + bk + c0;
  *(short8*)(dst) = o0;
  *(short8*)(dst + 8) = o1;
}

// 256x192-tile GEMM, 768 thr = 12 waves (4m x 3n, wave = 64x64, acc[4][4]).
// Double-buffered LDS + counted vmcnt (T3/T4, proven r20/r21). Staging:
// 3584 chunks -> 5 loads (waves 0-7) / 4 loads (waves 8-11); both the A/B
// boundary (2048) and the idle boundary (3584) land at wave-aligned tids,
// so wave-uniform LDS bases and per-wave vmcnt counts stay legal.
__global__ __launch_bounds__(768) void gemm192(const ushort* __restrict__ A,
                                               const ushort* __restrict__ Bt,
                                               ushort* __restrict__ C,
                                               int Ndim) {
  __shared__ char sA[2][32768];   // 256 rows x 128B, swizzled
  __shared__ char sB[2][24576];   // 192 rows x 128B, swizzled
  const int tid = threadIdx.x;
  const int lane = tid & 63, wid = tid >> 6;    // 12 waves
  const int wm = wid & 3, wn = wid >> 2;        // 4m x 3n
  const int lc = lane & 15, lg = lane >> 4;
  const int bm = blockIdx.x * 256, bn = blockIdx.y * 192;
  const int lane16 = lane << 4;

  f32x4 acc[4][4] = {};

#define STAGE192(tt, bb)                                                    \
  do {                                                                      \
    _Pragma("unroll") for (int i_ = 0; i_ < 5; ++i_) {                      \
      int c_ = tid + i_ * 768;                                              \
      if (c_ < 3584) {                                                      \
        if (c_ < 2048) {                                                    \
          int row_ = c_ >> 3;                                               \
          int cbl_ = (c_ & 7) << 4;                                         \
          int ce_ = (cbl_ ^ ((row_ & 7) << 4)) >> 1;                        \
          gload16(A + (size_t)(bm + row_) * 1024 + (tt) * 64 + ce_,         \
                  sA[bb] + ((c_ << 4) - lane16));                           \
        } else {                                                            \
          int c2_ = c_ - 2048;                                              \
          int row_ = c2_ >> 3;                                              \
          int cbl_ = (c2_ & 7) << 4;                                        \
          int ce_ = (cbl_ ^ ((row_ & 7) << 4)) >> 1;                        \
          gload16(Bt + (size_t)(bn + row_) * 1024 + (tt) * 64 + ce_,        \
                  sB[bb] + ((c2_ << 4) - lane16));                          \
        }                                                                   \
      }                                                                     \
    }                                                                       \
  } while (0)

  STAGE192(0, 0);
  STAGE192(1, 1);

  for (int t = 0; t < 16; ++t) {
    const int cur = t & 1;
    if (t < 15) {
      if (wid < 8) asm volatile("s_waitcnt vmcnt(5)" ::: "memory");
      else         asm volatile("s_waitcnt vmcnt(4)" ::: "memory");
    } else {
      asm volatile("s_waitcnt vmcnt(0)" ::: "memory");
    }
    __builtin_amdgcn_s_barrier();
    __builtin_amdgcn_sched_barrier(0);
#pragma unroll
    for (int ks = 0; ks < 2; ++ks) {
      const int kb = ks * 64 + lg * 16;
      short8 af[4], bf[4];
#pragma unroll
      for (int mf = 0; mf < 4; ++mf) {
        int row = wm * 64 + mf * 16 + lc;
        af[mf] = *(const short8*)&sA[cur][(row << 7) + (kb ^ ((row & 7) << 4))];
      }
#pragma unroll
      for (int nf = 0; nf < 4; ++nf) {
        int row = wn * 64 + nf * 16 + lc;
        bf[nf] = *(const short8*)&sB[cur][(row << 7) + (kb ^ ((row & 7) << 4))];
      }
      __builtin_amdgcn_s_setprio(1);
#pragma unroll
      for (int mf = 0; mf < 4; ++mf)
#pragma unroll
        for (int nf = 0; nf < 4; ++nf)
          acc[mf][nf] = mfma16(af[mf], bf[nf], acc[mf][nf]);
      __builtin_amdgcn_s_setprio(0);
    }
    asm volatile("s_waitcnt lgkmcnt(0)" ::: "memory");
    __builtin_amdgcn_sched_barrier(0);
    __builtin_amdgcn_s_barrier();
    __builtin_amdgcn_sched_barrier(0);
    if (t + 2 < 16) STAGE192(t + 2, cur);
  }
#undef STAGE192

#pragma unroll
  for (int mf = 0; mf < 4; ++mf) {
    int rowb = bm + wm * 64 + mf * 16 + lg * 4;
#pragma unroll
    for (int nf = 0; nf < 4; ++nf) {
      int col = bn + wn * 64 + nf * 16 + lc;
#pragma unroll
      for (int r = 0; r < 4; ++r)
        C[(size_t)(rowb + r) * Ndim + col] = f2bf(acc[mf][nf][r]);
    }
  }
}

// 128x128-tile GEMM, 512 thr = 8 waves (2m x 4n, wave = 64x32, acc[4][2]),
// double-buffered LDS + counted vmcnt. f32out selects C dtype.
__global__ __launch_bounds__(512) void gemm128p(const ushort* __restrict__ A,
                                                const ushort* __restrict__ Bt,
                                                void* __restrict__ Cv,
                                                int Ndim, int Kdim, int f32out) {
  __shared__ char sA[2][16384];
  __shared__ char sB[2][16384];
  const int tid = threadIdx.x;
  const int lane = tid & 63, wid = tid >> 6;
  const int wm = wid >> 2, wn = wid & 3;        // 2m x 4n
  const int lc = lane & 15, lg = lane >> 4;
  const int bm = blockIdx.x * 128, bn = blockIdx.y * 128;
  const int lane16 = lane << 4;
  const int nk = Kdim >> 6;

  f32x4 acc[4][2] = {};

#define STAGE128(tt, bb)                                                   \
  do {                                                                     \
    _Pragma("unroll") for (int i_ = 0; i_ < 2; ++i_) {                     \
      int c_ = tid + i_ * 512;            /* A chunks 0..1023 */           \
      int row_ = c_ >> 3;                                                  \
      int cbl_ = (c_ & 7) << 4;                                            \
      int ce_ = (cbl_ ^ ((row_ & 7) << 4)) >> 1;                           \
      gload16(A + (size_t)(bm + row_) * Kdim + (tt) * 64 + ce_,            \
              sA[bb] + ((c_ << 4) - lane16));                              \
    }                                                                      \
    _Pragma("unroll") for (int i_ = 0; i_ < 2; ++i_) {                     \
      int c_ = tid + i_ * 512;            /* B chunks 0..1023 */           \
      int row_ = c_ >> 3;                                                  \
      int cbl_ = (c_ & 7) << 4;                                            \
      int ce_ = (cbl_ ^ ((row_ & 7) << 4)) >> 1;                           \
      gload16(Bt + (size_t)(bn + row_) * Kdim + (tt) * 64 + ce_,           \
              sB[bb] + ((c_ << 4) - lane16));                              \
    }                                                                      \
  } while (0)

  STAGE128(0, 0);
  STAGE128(1, 1);

  for (int t = 0; t < nk; ++t) {
    const int cur = t & 1;
    if (t < nk - 1) asm volatile("s_waitcnt vmcnt(4)" ::: "memory");
    else            asm volatile("s_waitcnt vmcnt(0)" ::: "memory");
    __builtin_amdgcn_s_barrier();
    __builtin_amdgcn_sched_barrier(0);
#pragma unroll
    for (int ks = 0; ks < 2; ++ks) {
      const int kb = ks * 64 + lg * 16;
      short8 af[4], bfr[2];
#pragma unroll
      for (int m = 0; m < 4; ++m) {
        int row = wm * 64 + m * 16 + lc;
        af[m] = *(const short8*)&sA[cur][(row << 7) + (kb ^ ((row & 7) << 4))];
      }
#pragma unroll
      for (int n = 0; n < 2; ++n) {
        int row = wn * 32 + n * 16 + lc;
        bfr[n] = *(const short8*)&sB[cur][(row << 7) + (kb ^ ((row & 7) << 4))];
      }
      __builtin_amdgcn_s_setprio(1);
#pragma unroll
      for (int m = 0; m < 4; ++m)
#pragma unroll
        for (int n = 0; n < 2; ++n)
          acc[m][n] = mfma16(af[m], bfr[n], acc[m][n]);
      __builtin_amdgcn_s_setprio(0);
    }
    asm volatile("s_waitcnt lgkmcnt(0)" ::: "memory");
    __builtin_amdgcn_sched_barrier(0);
    __builtin_amdgcn_s_barrier();
    __builtin_amdgcn_sched_barrier(0);
    if (t + 2 < nk) STAGE128(t + 2, cur);
  }
#undef STAGE128

#pragma unroll
  for (int m = 0; m < 4; ++m) {
    int rowb = bm + wm * 64 + m * 16 + lg * 4;
#pragma unroll
    for (int n = 0; n < 2; ++n) {
      int col = bn + wn * 32 + n * 16 + lc;
      if (f32out) {
        float* C = (float*)Cv;
#pragma unroll
        for (int r = 0; r < 4; ++r)
          C[(size_t)(rowb + r) * Ndim + col] = acc[m][n][r];
      } else {
        ushort* C = (ushort*)Cv;
#pragma unroll
        for (int r = 0; r < 4; ++r)
          C[(size_t)(rowb + r) * Ndim + col] = f2bf(acc[m][n][r]);
      }
    }
  }
}

// Flash attention (round-17 proven: 52.9 us): 512 thr / 8 waves x 16 q rows,
// bijective slot map (causal pairing t/15-t per CU + XCD locality), 2
// barriers/iter, reg-prefetched K/V, swapped QK^T, fixed-max softmax,
// deferred denominator, cvt_pk P-pack via per-wave LDS.
__global__ __launch_bounds__(512) void attn_k(const ushort* __restrict__ qkv,
                                              ushort* __restrict__ Y) {
  __shared__ char sK[8192];
  __shared__ char sV[8192];
  __shared__ char sP[16384];
  __shared__ float sL[8][16];
  const int tid = threadIdx.x;
  const int lane = tid & 63, wid = tid >> 6;
  const int lc = lane & 15, lg = lane >> 4;
  const int orig = blockIdx.x;
  const int xcd = orig & 7, slot = orig >> 3;
  int tile, bhl;
  if (slot < 32) { tile = slot >> 2;              bhl = slot & 3; }
  else           { tile = 15 - ((slot - 32) >> 2); bhl = (slot - 32) & 3; }
  const int bh = xcd * 4 + bhl;
  const int b = bh >> 4, h = bh & 15;
  char* sPw = sP + (wid << 11);

  const ushort* base = qkv + (size_t)b * T_SEQ * 3072 + h * 64;
  const int q0 = tile * 128 + wid * 16;

  const int kt = tid >> 3, kce = (tid & 7) << 3, kcb = kce << 1;
  const int ksw = (kt & 7) << 4;
  const int vt = tid & 63, vd0 = (tid >> 6) << 3;
  const ushort* kbase = base + 1024;
  const ushort* vbase = base + 2048;

  short8 qf[2];
#pragma unroll
  for (int ks = 0; ks < 2; ++ks)
    qf[ks] = *(const short8*)(base + (size_t)(q0 + lc) * 3072 + ks * 32 + lg * 8);

  f32x4 o[4] = {};
  float lsum = 0.f;

  const float cexp = 0.125f * 1.4426950408889634f;
  const int nkb = 2 * (tile + 1);
  const int qmaxw = q0 + 15;

  short8 kr = *(const short8*)(kbase + (size_t)kt * 3072 + kce);
  short8 vr = *(const short8*)(vbase + (size_t)vt * 3072 + vd0);

  for (int kb = 0; kb < nkb; ++kb) {
    __syncthreads();
    *(short8*)&sK[(kt << 7) + (kcb ^ ksw)] = kr;
#pragma unroll
    for (int j = 0; j < 8; ++j) {
      int d = vd0 + j;
      *(ushort*)&sV[(d << 7) + ((2 * vt) ^ ((d & 7) << 4))] = ((const ushort*)&vr)[j];
    }
    __syncthreads();
    if (kb + 1 < nkb) {
      kr = *(const short8*)(kbase + (size_t)((kb + 1) * 64 + kt) * 3072 + kce);
      vr = *(const short8*)(vbase + (size_t)((kb + 1) * 64 + vt) * 3072 + vd0);
    }
    if (kb * 64 > qmaxw) continue;

    f32x4 S[4] = {};
    __builtin_amdgcn_s_setprio(1);
#pragma unroll
    for (int ks = 0; ks < 2; ++ks) {
      int kbyt = ks * 64 + lg * 16;
      short8 kf[4];
#pragma unroll
      for (int n = 0; n < 4; ++n) {
        int row = n * 16 + lc;
        kf[n] = *(const short8*)&sK[(row << 7) + (kbyt ^ ((row & 7) << 4))];
      }
#pragma unroll
      for (int n = 0; n < 4; ++n)
        S[n] = mfma16(kf[n], qf[ks], S[n]);
    }
    __builtin_amdgcn_s_setprio(0);

    const bool diag = (kb * 64 + 63 > q0);
    {
      int q = q0 + lc;
      float lacc = 0.f;
#pragma unroll
      for (int n = 0; n < 4; ++n) {
        int kg = kb * 64 + n * 16 + lg * 4;
        f32x4 pe;
#pragma unroll
        for (int r = 0; r < 4; ++r) {
          pe[r] = exp2f(S[n][r] * cexp);
          if (diag && (kg + r > q)) pe[r] = 0.f;
        }
        lacc += (pe[0] + pe[1]) + (pe[2] + pe[3]);
        u32x2 w;
        w[0] = cvtpk(pe[0], pe[1]);
        w[1] = cvtpk(pe[2], pe[3]);
        int colb = n * 32 + lg * 8;
        *(u32x2*)&sPw[(lc << 7) + (colb ^ ((lc & 7) << 4))] = w;
      }
      lsum += lacc;
    }
    asm volatile("" ::: "memory");
    __builtin_amdgcn_s_setprio(1);
#pragma unroll
    for (int ks = 0; ks < 2; ++ks) {
      int kbyt = ks * 64 + lg * 16;
      short8 pf = *(const short8*)&sPw[(lc << 7) + (kbyt ^ ((lc & 7) << 4))];
      short8 vf[4];
#pragma unroll
      for (int dn = 0; dn < 4; ++dn) {
        int row = dn * 16 + lc;
        vf[dn] = *(const short8*)&sV[(row << 7) + (kbyt ^ ((row & 7) << 4))];
      }
#pragma unroll
      for (int dn = 0; dn < 4; ++dn)
        o[dn] = mfma16(pf, vf[dn], o[dn]);
    }
    __builtin_amdgcn_s_setprio(0);
  }
  {
    float v = lsum;
    v += __shfl_xor(v, 16);
    v += __shfl_xor(v, 32);
    sL[wid][lc] = 1.0f / v;
  }
  asm volatile("" ::: "memory");
  {
    float lr[4];
#pragma unroll
    for (int r = 0; r < 4; ++r) lr[r] = sL[wid][lg * 4 + r];
#pragma unroll
    for (int dn = 0; dn < 4; ++dn) {
#pragma unroll
      for (int r = 0; r < 4; ++r) {
        int t = q0 + lg * 4 + r;
        Y[(size_t)(b * T_SEQ + t) * 1024 + h * 64 + dn * 16 + lc] =
            f2bf(o[dn][r] * lr[r]);
      }
    }
  }
}

extern "C" void kernel_launch(void* const* d_in, const int* in_sizes, int n_in,
                              void* d_out, int out_size, void* d_ws, size_t ws_size,
                              hipStream_t stream) {
  const float* x    = (const float*)d_in[0];
  const float* Wqkv = (const float*)d_in[1];
  const float* Wo   = (const float*)d_in[2];
  for (int i = 0; i < n_in; ++i) {
    if (in_sizes[i] == 4194304) x = (const float*)d_in[i];
    else if (in_sizes[i] == 3145728) Wqkv = (const float*)d_in[i];
    else if (in_sizes[i] == 1048576) Wo = (const float*)d_in[i];
  }
  float* out = (float*)d_out;

  ushort* xb    = (ushort*)d_ws;                       // [4096][1024] bf16
  ushort* WqkvT = xb + (size_t)4096 * 1024;            // [3072][1024]
  ushort* WoT   = WqkvT + (size_t)3072 * 1024;         // [1024][1024]
  ushort* QKV   = WoT + (size_t)1024 * 1024;           // [4096][3072]
  ushort* Yb    = QKV + (size_t)4096 * 3072;           // [4096][1024]

  prep_k<<<3072, 256, 0, stream>>>(x, Wqkv, Wo, xb, WqkvT, WoT);
  gemm192<<<dim3(16, 16), 768, 0, stream>>>(xb, WqkvT, QKV, 3072);
  attn_k<<<512, 512, 0, stream>>>(QKV, Yb);
  gemm128p<<<dim3(32, 8), 512, 0, stream>>>(Yb, WoT, out, 1024, 1024, 1);
}

// Round 24
// 106.129 us; speedup vs baseline: 1.1087x; 1.0249x over previous
//
#include <hip/hip_runtime.h>
#include <stdint.h>

typedef __attribute__((ext_vector_type(8))) short short8;
typedef __attribute__((ext_vector_type(8))) __bf16 bf16x8;
typedef __attribute__((ext_vector_type(4))) float f32x4;
typedef __attribute__((ext_vector_type(2))) unsigned int u32x2;

#define T_SEQ 2048

// round-to-nearest-even f32 -> bf16
static __device__ __forceinline__ ushort f2bf(float f) {
  uint32_t u = __float_as_uint(f);
  u += 0x7fffu + ((u >> 16) & 1u);
  return (ushort)(u >> 16);
}

// packed f32x2 -> bf16x2 (low = lo, high = hi), HW RNE
static __device__ __forceinline__ uint32_t cvtpk(float lo, float hi) {
  uint32_t r;
  asm("v_cvt_pk_bf16_f32 %0, %1, %2" : "=v"(r) : "v"(lo), "v"(hi));
  return r;
}

static __device__ __forceinline__ f32x4 mfma16(short8 a, short8 b, f32x4 c) {
  return __builtin_amdgcn_mfma_f32_16x16x32_bf16(
      __builtin_bit_cast(bf16x8, a), __builtin_bit_cast(bf16x8, b), c, 0, 0, 0);
}

// async global->LDS, 16B per lane; lds base must be wave-uniform
static __device__ __forceinline__ void gload16(const ushort* g, char* l) {
  __builtin_amdgcn_global_load_lds(
      (const __attribute__((address_space(1))) void*)g,
      (__attribute__((address_space(3))) void*)l, 16, 0, 0);
}

// Fused prologue: blocks <2048 convert x f32->bf16 (8 elems/thread);
// blocks >=2048 transpose+convert Wqkv (tb<768) / Wo into [N][K] bf16.
__global__ __launch_bounds__(256) void prep_k(const float* __restrict__ x,
                                              const float* __restrict__ Wqkv,
                                              const float* __restrict__ Wo,
                                              ushort* __restrict__ xb,
                                              ushort* __restrict__ WqkvT,
                                              ushort* __restrict__ WoT) {
  if (blockIdx.x < 2048) {
    int i = (blockIdx.x * 256 + threadIdx.x) * 8;
    float4 a = *(const float4*)(x + i);
    float4 b = *(const float4*)(x + i + 4);
    short8 o;
    ((ushort*)&o)[0] = f2bf(a.x); ((ushort*)&o)[1] = f2bf(a.y);
    ((ushort*)&o)[2] = f2bf(a.z); ((ushort*)&o)[3] = f2bf(a.w);
    ((ushort*)&o)[4] = f2bf(b.x); ((ushort*)&o)[5] = f2bf(b.y);
    ((ushort*)&o)[6] = f2bf(b.z); ((ushort*)&o)[7] = f2bf(b.w);
    *(short8*)(xb + i) = o;
    return;
  }
  __shared__ ushort t[64][65];
  int tb = blockIdx.x - 2048;       // 0..1023
  const float* in;
  ushort* out;
  int N, byl;
  if (tb < 768) { in = Wqkv; out = WqkvT; N = 3072; byl = tb >> 4; }
  else          { in = Wo;   out = WoT;   N = 1024; byl = (tb - 768) >> 4; }
  const int K = 1024;
  const int bk = (tb & 15) * 64, bn = byl * 64;
  const int r = threadIdx.x >> 2, c0 = (threadIdx.x & 3) << 4;
  const float* src = in + (size_t)(bk + r) * N + bn + c0;
#pragma unroll
  for (int q = 0; q < 4; ++q) {
    float4 a = *(const float4*)(src + q * 4);
    t[r][c0 + q * 4 + 0] = f2bf(a.x);
    t[r][c0 + q * 4 + 1] = f2bf(a.y);
    t[r][c0 + q * 4 + 2] = f2bf(a.z);
    t[r][c0 + q * 4 + 3] = f2bf(a.w);
  }
  __syncthreads();
  short8 o0, o1;
#pragma unroll
  for (int j = 0; j < 8; ++j) {
    ((ushort*)&o0)[j] = t[c0 + j][r];
    ((ushort*)&o1)[j] = t[c0 + 8 + j][r];
  }
  ushort* dst = out + (size_t)(bn + r) * K + bk + c0;
  *(short8*)(dst) = o0;
  *(short8*)(dst + 8) = o1;
}

// 256x192-tile GEMM, 1024 thr = 16 waves (4m x 4n, wave = 64x48, acc[4][3]).
// Double-buffered LDS + counted vmcnt. Staging: 3584 chunks over 4 passes of
// 1024; A/B boundary (2048) and tail (3584 = 3*1024+512) are wave-aligned,
// so wave-uniform LDS bases and per-wave vmcnt counts (4 / 3) stay legal.
__global__ __launch_bounds__(1024) void gemm192(const ushort* __restrict__ A,
                                                const ushort* __restrict__ Bt,
                                                ushort* __restrict__ C,
                                                int Ndim) {
  __shared__ char sA[2][32768];   // 256 rows x 128B, swizzled
  __shared__ char sB[2][24576];   // 192 rows x 128B, swizzled
  const int tid = threadIdx.x;
  const int lane = tid & 63, wid = tid >> 6;    // 16 waves
  const int wm = wid >> 2, wn = wid & 3;        // 4m x 4n
  const int lc = lane & 15, lg = lane >> 4;
  const int bm = blockIdx.x * 256, bn = blockIdx.y * 192;
  const int lane16 = lane << 4;

  f32x4 acc[4][3] = {};

#define STAGE192(tt, bb)                                                    \
  do {                                                                      \
    _Pragma("unroll") for (int i_ = 0; i_ < 4; ++i_) {                      \
      int c_ = tid + i_ * 1024;                                             \
      if (c_ < 3584) {                                                      \
        if (c_ < 2048) {                                                    \
          int row_ = c_ >> 3;                                               \
          int cbl_ = (c_ & 7) << 4;                                         \
          int ce_ = (cbl_ ^ ((row_ & 7) << 4)) >> 1;                        \
          gload16(A + (size_t)(bm + row_) * 1024 + (tt) * 64 + ce_,         \
                  sA[bb] + ((c_ << 4) - lane16));                           \
        } else {                                                            \
          int c2_ = c_ - 2048;                                              \
          int row_ = c2_ >> 3;                                              \
          int cbl_ = (c2_ & 7) << 4;                                        \
          int ce_ = (cbl_ ^ ((row_ & 7) << 4)) >> 1;                        \
          gload16(Bt + (size_t)(bn + row_) * 1024 + (tt) * 64 + ce_,        \
                  sB[bb] + ((c2_ << 4) - lane16));                          \
        }                                                                   \
      }                                                                     \
    }                                                                       \
  } while (0)

  STAGE192(0, 0);
  STAGE192(1, 1);

  for (int t = 0; t < 16; ++t) {
    const int cur = t & 1;
    if (t < 15) {
      if (wid < 8) asm volatile("s_waitcnt vmcnt(4)" ::: "memory");
      else         asm volatile("s_waitcnt vmcnt(3)" ::: "memory");
    } else {
      asm volatile("s_waitcnt vmcnt(0)" ::: "memory");
    }
    __builtin_amdgcn_s_barrier();
    __builtin_amdgcn_sched_barrier(0);
#pragma unroll
    for (int ks = 0; ks < 2; ++ks) {
      const int kb = ks * 64 + lg * 16;
      short8 af[4], bf[3];
#pragma unroll
      for (int mf = 0; mf < 4; ++mf) {
        int row = wm * 64 + mf * 16 + lc;
        af[mf] = *(const short8*)&sA[cur][(row << 7) + (kb ^ ((row & 7) << 4))];
      }
#pragma unroll
      for (int nf = 0; nf < 3; ++nf) {
        int row = wn * 48 + nf * 16 + lc;
        bf[nf] = *(const short8*)&sB[cur][(row << 7) + (kb ^ ((row & 7) << 4))];
      }
      __builtin_amdgcn_s_setprio(1);
#pragma unroll
      for (int mf = 0; mf < 4; ++mf)
#pragma unroll
        for (int nf = 0; nf < 3; ++nf)
          acc[mf][nf] = mfma16(af[mf], bf[nf], acc[mf][nf]);
      __builtin_amdgcn_s_setprio(0);
    }
    asm volatile("s_waitcnt lgkmcnt(0)" ::: "memory");
    __builtin_amdgcn_sched_barrier(0);
    __builtin_amdgcn_s_barrier();
    __builtin_amdgcn_sched_barrier(0);
    if (t + 2 < 16) STAGE192(t + 2, cur);
  }
#undef STAGE192

#pragma unroll
  for (int mf = 0; mf < 4; ++mf) {
    int rowb = bm + wm * 64 + mf * 16 + lg * 4;
#pragma unroll
    for (int nf = 0; nf < 3; ++nf) {
      int col = bn + wn * 48 + nf * 16 + lc;
#pragma unroll
      for (int r = 0; r < 4; ++r)
        C[(size_t)(rowb + r) * Ndim + col] = f2bf(acc[mf][nf][r]);
    }
  }
}

// 128x128-tile GEMM, 1024 thr = 16 waves (4m x 4n, wave = 32x32, acc[2][2]),
// double-buffered LDS + counted vmcnt. Staging: pass 0 = A (1024 chunks),
// pass 1 = B (1024 chunks) -> 2 loads/thread, entry vmcnt(2).
__global__ __launch_bounds__(1024) void gemm128p(const ushort* __restrict__ A,
                                                 const ushort* __restrict__ Bt,
                                                 void* __restrict__ Cv,
                                                 int Ndim, int Kdim, int f32out) {
  __shared__ char sA[2][16384];
  __shared__ char sB[2][16384];
  const int tid = threadIdx.x;
  const int lane = tid & 63, wid = tid >> 6;
  const int wm = wid >> 2, wn = wid & 3;        // 4m x 4n
  const int lc = lane & 15, lg = lane >> 4;
  const int bm = blockIdx.x * 128, bn = blockIdx.y * 128;
  const int lane16 = lane << 4;
  const int nk = Kdim >> 6;

  f32x4 acc[2][2] = {};

#define STAGE128(tt, bb)                                                   \
  do {                                                                     \
    {                                                                      \
      int c_ = tid;                       /* A chunks 0..1023 */           \
      int row_ = c_ >> 3;                                                  \
      int cbl_ = (c_ & 7) << 4;                                            \
      int ce_ = (cbl_ ^ ((row_ & 7) << 4)) >> 1;                           \
      gload16(A + (size_t)(bm + row_) * Kdim + (tt) * 64 + ce_,            \
              sA[bb] + ((c_ << 4) - lane16));                              \
    }                                                                      \
    {                                                                      \
      int c_ = tid;                       /* B chunks 0..1023 */           \
      int row_ = c_ >> 3;                                                  \
      int cbl_ = (c_ & 7) << 4;                                            \
      int ce_ = (cbl_ ^ ((row_ & 7) << 4)) >> 1;                           \
      gload16(Bt + (size_t)(bn + row_) * Kdim + (tt) * 64 + ce_,           \
              sB[bb] + ((c_ << 4) - lane16));                              \
    }                                                                      \
  } while (0)

  STAGE128(0, 0);
  STAGE128(1, 1);

  for (int t = 0; t < nk; ++t) {
    const int cur = t & 1;
    if (t < nk - 1) asm volatile("s_waitcnt vmcnt(2)" ::: "memory");
    else            asm volatile("s_waitcnt vmcnt(0)" ::: "memory");
    __builtin_amdgcn_s_barrier();
    __builtin_amdgcn_sched_barrier(0);
#pragma unroll
    for (int ks = 0; ks < 2; ++ks) {
      const int kb = ks * 64 + lg * 16;
      short8 af[2], bfr[2];
#pragma unroll
      for (int m = 0; m < 2; ++m) {
        int row = wm * 32 + m * 16 + lc;
        af[m] = *(const short8*)&sA[cur][(row << 7) + (kb ^ ((row & 7) << 4))];
      }
#pragma unroll
      for (int n = 0; n < 2; ++n) {
        int row = wn * 32 + n * 16 + lc;
        bfr[n] = *(const short8*)&sB[cur][(row << 7) + (kb ^ ((row & 7) << 4))];
      }
      __builtin_amdgcn_s_setprio(1);
#pragma unroll
      for (int m = 0; m < 2; ++m)
#pragma unroll
        for (int n = 0; n < 2; ++n)
          acc[m][n] = mfma16(af[m], bfr[n], acc[m][n]);
      __builtin_amdgcn_s_setprio(0);
    }
    asm volatile("s_waitcnt lgkmcnt(0)" ::: "memory");
    __builtin_amdgcn_sched_barrier(0);
    __builtin_amdgcn_s_barrier();
    __builtin_amdgcn_sched_barrier(0);
    if (t + 2 < nk) STAGE128(t + 2, cur);
  }
#undef STAGE128

#pragma unroll
  for (int m = 0; m < 2; ++m) {
    int rowb = bm + wm * 32 + m * 16 + lg * 4;
#pragma unroll
    for (int n = 0; n < 2; ++n) {
      int col = bn + wn * 32 + n * 16 + lc;
      if (f32out) {
        float* C = (float*)Cv;
#pragma unroll
        for (int r = 0; r < 4; ++r)
          C[(size_t)(rowb + r) * Ndim + col] = acc[m][n][r];
      } else {
        ushort* C = (ushort*)Cv;
#pragma unroll
        for (int r = 0; r < 4; ++r)
          C[(size_t)(rowb + r) * Ndim + col] = f2bf(acc[m][n][r]);
      }
    }
  }
}

// Flash attention (round-17 proven: 52.9 us): 512 thr / 8 waves x 16 q rows,
// bijective slot map (causal pairing t/15-t per CU + XCD locality), 2
// barriers/iter, reg-prefetched K/V, swapped QK^T, fixed-max softmax,
// deferred denominator, cvt_pk P-pack via per-wave LDS.
__global__ __launch_bounds__(512) void attn_k(const ushort* __restrict__ qkv,
                                              ushort* __restrict__ Y) {
  __shared__ char sK[8192];
  __shared__ char sV[8192];
  __shared__ char sP[16384];
  __shared__ float sL[8][16];
  const int tid = threadIdx.x;
  const int lane = tid & 63, wid = tid >> 6;
  const int lc = lane & 15, lg = lane >> 4;
  const int orig = blockIdx.x;
  const int xcd = orig & 7, slot = orig >> 3;
  int tile, bhl;
  if (slot < 32) { tile = slot >> 2;              bhl = slot & 3; }
  else           { tile = 15 - ((slot - 32) >> 2); bhl = (slot - 32) & 3; }
  const int bh = xcd * 4 + bhl;
  const int b = bh >> 4, h = bh & 15;
  char* sPw = sP + (wid << 11);

  const ushort* base = qkv + (size_t)b * T_SEQ * 3072 + h * 64;
  const int q0 = tile * 128 + wid * 16;

  const int kt = tid >> 3, kce = (tid & 7) << 3, kcb = kce << 1;
  const int ksw = (kt & 7) << 4;
  const int vt = tid & 63, vd0 = (tid >> 6) << 3;
  const ushort* kbase = base + 1024;
  const ushort* vbase = base + 2048;

  short8 qf[2];
#pragma unroll
  for (int ks = 0; ks < 2; ++ks)
    qf[ks] = *(const short8*)(base + (size_t)(q0 + lc) * 3072 + ks * 32 + lg * 8);

  f32x4 o[4] = {};
  float lsum = 0.f;

  const float cexp = 0.125f * 1.4426950408889634f;
  const int nkb = 2 * (tile + 1);
  const int qmaxw = q0 + 15;

  short8 kr = *(const short8*)(kbase + (size_t)kt * 3072 + kce);
  short8 vr = *(const short8*)(vbase + (size_t)vt * 3072 + vd0);

  for (int kb = 0; kb < nkb; ++kb) {
    __syncthreads();
    *(short8*)&sK[(kt << 7) + (kcb ^ ksw)] = kr;
#pragma unroll
    for (int j = 0; j < 8; ++j) {
      int d = vd0 + j;
      *(ushort*)&sV[(d << 7) + ((2 * vt) ^ ((d & 7) << 4))] = ((const ushort*)&vr)[j];
    }
    __syncthreads();
    if (kb + 1 < nkb) {
      kr = *(const short8*)(kbase + (size_t)((kb + 1) * 64 + kt) * 3072 + kce);
      vr = *(const short8*)(vbase + (size_t)((kb + 1) * 64 + vt) * 3072 + vd0);
    }
    if (kb * 64 > qmaxw) continue;

    f32x4 S[4] = {};
    __builtin_amdgcn_s_setprio(1);
#pragma unroll
    for (int ks = 0; ks < 2; ++ks) {
      int kbyt = ks * 64 + lg * 16;
      short8 kf[4];
#pragma unroll
      for (int n = 0; n < 4; ++n) {
        int row = n * 16 + lc;
        kf[n] = *(const short8*)&sK[(row << 7) + (kbyt ^ ((row & 7) << 4))];
      }
#pragma unroll
      for (int n = 0; n < 4; ++n)
        S[n] = mfma16(kf[n], qf[ks], S[n]);
    }
    __builtin_amdgcn_s_setprio(0);

    const bool diag = (kb * 64 + 63 > q0);
    {
      int q = q0 + lc;
      float lacc = 0.f;
#pragma unroll
      for (int n = 0; n < 4; ++n) {
        int kg = kb * 64 + n * 16 + lg * 4;
        f32x4 pe;
#pragma unroll
        for (int r = 0; r < 4; ++r) {
          pe[r] = exp2f(S[n][r] * cexp);
          if (diag && (kg + r > q)) pe[r] = 0.f;
        }
        lacc += (pe[0] + pe[1]) + (pe[2] + pe[3]);
        u32x2 w;
        w[0] = cvtpk(pe[0], pe[1]);
        w[1] = cvtpk(pe[2], pe[3]);
        int colb = n * 32 + lg * 8;
        *(u32x2*)&sPw[(lc << 7) + (colb ^ ((lc & 7) << 4))] = w;
      }
      lsum += lacc;
    }
    asm volatile("" ::: "memory");
    __builtin_amdgcn_s_setprio(1);
#pragma unroll
    for (int ks = 0; ks < 2; ++ks) {
      int kbyt = ks * 64 + lg * 16;
      short8 pf = *(const short8*)&sPw[(lc << 7) + (kbyt ^ ((lc & 7) << 4))];
      short8 vf[4];
#pragma unroll
      for (int dn = 0; dn < 4; ++dn) {
        int row = dn * 16 + lc;
        vf[dn] = *(const short8*)&sV[(row << 7) + (kbyt ^ ((row & 7) << 4))];
      }
#pragma unroll
      for (int dn = 0; dn < 4; ++dn)
        o[dn] = mfma16(pf, vf[dn], o[dn]);
    }
    __builtin_amdgcn_s_setprio(0);
  }
  {
    float v = lsum;
    v += __shfl_xor(v, 16);
    v += __shfl_xor(v, 32);
    sL[wid][lc] = 1.0f / v;
  }
  asm volatile("" ::: "memory");
  {
    float lr[4];
#pragma unroll
    for (int r = 0; r < 4; ++r) lr[r] = sL[wid][lg * 4 + r];
#pragma unroll
    for (int dn = 0; dn < 4; ++dn) {
#pragma unroll
      for (int r = 0; r < 4; ++r) {
        int t = q0 + lg * 4 + r;
        Y[(size_t)(b * T_SEQ + t) * 1024 + h * 64 + dn * 16 + lc] =
            f2bf(o[dn][r] * lr[r]);
      }
    }
  }
}

extern "C" void kernel_launch(void* const* d_in, const int* in_sizes, int n_in,
                              void* d_out, int out_size, void* d_ws, size_t ws_size,
                              hipStream_t stream) {
  const float* x    = (const float*)d_in[0];
  const float* Wqkv = (const float*)d_in[1];
  const float* Wo   = (const float*)d_in[2];
  for (int i = 0; i < n_in; ++i) {
    if (in_sizes[i] == 4194304) x = (const float*)d_in[i];
    else if (in_sizes[i] == 3145728) Wqkv = (const float*)d_in[i];
    else if (in_sizes[i] == 1048576) Wo = (const float*)d_in[i];
  }
  float* out = (float*)d_out;

  ushort* xb    = (ushort*)d_ws;                       // [4096][1024] bf16
  ushort* WqkvT = xb + (size_t)4096 * 1024;            // [3072][1024]
  ushort* WoT   = WqkvT + (size_t)3072 * 1024;         // [1024][1024]
  ushort* QKV   = WoT + (size_t)1024 * 1024;           // [4096][3072]
  ushort* Yb    = QKV + (size_t)4096 * 3072;           // [4096][1024]

  prep_k<<<3072, 256, 0, stream>>>(x, Wqkv, Wo, xb, WqkvT, WoT);
  gemm192<<<dim3(16, 16), 1024, 0, stream>>>(xb, WqkvT, QKV, 3072);
  attn_k<<<512, 512, 0, stream>>>(QKV, Yb);
  gemm128p<<<dim3(32, 8), 1024, 0, stream>>>(Yb, WoT, out, 1024, 1024, 1);
}